// Round 10
// baseline (214.960 us; speedup 1.0000x reference)
//
#include <hip/hip_runtime.h>
#include <math.h>

// ---------------------------------------------------------------------------
// MultiHeadAttention, B=4 H=16 S=2048 D=1024 (d=64), fp32 in/out.
//
// Algebra (verified r1-r10): mask softmax-shift-invariant -> dropped.
// q==k (shared Dense). M = W W^T symmetric, u = W b.
// S_ij = (x_i M + u).x_j (mod per-row const); u folds into T along dd.
// Second matmul uses x_h itself. No max-sub needed (scores O(+-1)).
//
// r16: T15 double-pipeline on the r13/r15 8-wave attn (82.5us verified).
// Evidence: r4 (8 w/CU, DS 40%) == r13 (16 w/CU, DS 78%) == ~83us -> binder
// is the barrier-locked serial chain S->exp2->cvt->PV (all waves in the same
// phase). Fix: slot t = {vmcnt(2); s_barrier; stage(t+2); S(t)->Scur;
// softmax+PV(t-1)<-Sprev}. Prev tile's VALU overlaps current tile's S-MFMA.
//  * 4 staging buffers (16KB each; live set = stage(t+2) wr, stage(t+1)
//    landing, S(t) rd, PV(t-1) rd). LDS 66.6KB -> still 2 blocks/CU.
//  * counted vmcnt(2) (stage=2 dma/wave), never 0 mid-loop; raw s_barrier +
//    sched_barrier(0) (rule #18). Scheme correctness-proven in r12 (passed).
//  * double Sacc SA/SB: r13 used 64 VGPR; +32 fits (512,4)'s 128 cap.
//    r12's spill was the mt=2 geometry (~190+64). Watch WRITE_SIZE.
// prex = r15 (exhausted: r7->r9 prex rewrites moved total ~1us; residual is
// harness reset cost). Kernel boundary prex|attn = cross-XCD flush (G16).
// Grid dim3(64 bh, 8 qt): XCD-local slices (r8: FETCH -7x).
// ---------------------------------------------------------------------------

#define S_LEN   2048
#define D_MODEL 1024
#define HD      64
#define NHEAD   16
#define QT      256
#define KT2     64
#define NKT     (S_LEN / KT2)   // 32

typedef __bf16 bf16;
typedef __bf16 bf16x8 __attribute__((ext_vector_type(8)));
typedef __bf16 bf16x4 __attribute__((ext_vector_type(4)));
typedef __bf16 bf16x2 __attribute__((ext_vector_type(2)));
typedef float  floatx16 __attribute__((ext_vector_type(16)));
typedef unsigned int u32;
typedef u32 u32x4 __attribute__((ext_vector_type(4)));

#define SCALE 0.02254211001389005324f   // log2(e)/64

__device__ __forceinline__ floatx16 mfma32(bf16x8 a, bf16x8 b, floatx16 c) {
    return __builtin_amdgcn_mfma_f32_32x32x16_bf16(a, b, c, 0, 0, 0);
}

__device__ __forceinline__ void ldsdma16(void* lds_base, const void* gsrc) {
    __builtin_amdgcn_global_load_lds(
        (const __attribute__((address_space(1))) u32*)gsrc,
        (__attribute__((address_space(3))) u32*)lds_base, 16, 0, 0);
}

__device__ __forceinline__ u32 pack2(bf16 lo, bf16 hi) {
    bf16x2 p = { lo, hi };
    return __builtin_bit_cast(u32, p);
}

__device__ __forceinline__ u32 cvtpk(float lo, float hi) {
    u32 r;
    asm("v_cvt_pk_bf16_f32 %0, %1, %2" : "=v"(r) : "v"(lo), "v"(hi));
    return r;
}
// swaps: x[32:63] <-> y[0:31].  After: x = {x.lo, y.lo}, y = {x.hi, y.hi}.
__device__ __forceinline__ void swap32(u32& x, u32& y) {
    asm("v_permlane32_swap_b32 %0, %1" : "+v"(x), "+v"(y));
}

#define VMCNT_WAIT(n) do { \
    asm volatile("s_waitcnt vmcnt(" #n ")" ::: "memory"); \
    __builtin_amdgcn_sched_barrier(0); } while (0)
#define BARRIER() do { __builtin_amdgcn_s_barrier(); \
    __builtin_amdgcn_sched_barrier(0); } while (0)

// ---------------------------------------------------------------------------
// prex (r15, verified): st64<32 -> Xb/XT for one 64-row s-tile;
// st64==32 (h==0,b==0) -> M' = W W^T * SCALE and u' = W b * SCALE.
// ---------------------------------------------------------------------------
__global__ __launch_bounds__(256)
void prex_kernel(const float* __restrict__ x, const float* __restrict__ W,
                 const float* __restrict__ bvec,
                 bf16* __restrict__ Xb, bf16* __restrict__ XT,
                 float* __restrict__ Uout, bf16* __restrict__ Mout) {
    __shared__ __align__(16) char smem[16896];
    u32*   sT = (u32*)smem;               // [64 dd][33] u32 (s-pairs), 8448 B
    float* Wp = (float*)smem;             // prep overlay: [64][65] fp32, 16640 B
    float* bs = (float*)(smem + 16640);   // prep overlay: 64 fp32, 256 B

    const int tid = threadIdx.x;
    const int st64 = blockIdx.x, h = blockIdx.y, b = blockIdx.z;

    if (st64 == 32) {                      // fused prep block
        if (h != 0 || b != 0) return;
        for (int i = tid; i < 4096; i += 256) Wp[(i >> 6) * 65 + (i & 63)] = W[i];
        if (tid < 64) bs[tid] = bvec[tid];
        __syncthreads();
        for (int e = tid; e < 4096; e += 256) {
            int i = e >> 6, j = e & 63;
            float acc = 0.f;
            #pragma unroll 8
            for (int c = 0; c < 64; ++c) acc += Wp[i * 65 + c] * Wp[j * 65 + c];
            Mout[e] = (bf16)(acc * SCALE);
        }
        if (tid < 64) {
            float acc = 0.f;
            #pragma unroll 8
            for (int c = 0; c < 64; ++c) acc += Wp[tid * 65 + c] * bs[c];
            Uout[tid] = acc * SCALE;
        }
        return;
    }

    const int bh = b * NHEAD + h;
    const float* xbh = x + (size_t)b * S_LEN * D_MODEL +
                       (size_t)st64 * 64 * D_MODEL + h * HD;
    bf16* Xbbh = Xb + ((size_t)bh * S_LEN + st64 * 64) * HD;

    const int t  = tid & 15;       // column group: c4 = 4t (floats)
    const int rp = tid >> 4;       // row-pair index within a 32-row slab
    const int c4 = t * 4;

    // ---- Phase A: ALL loads first (4x float4 in flight), then convert ----
    float4 va[2][2];
    #pragma unroll
    for (int it = 0; it < 2; ++it)
        #pragma unroll
        for (int k = 0; k < 2; ++k)
            va[it][k] = *(const float4*)(xbh +
                (size_t)(it * 32 + rp * 2 + k) * D_MODEL + c4);

    #pragma unroll
    for (int it = 0; it < 2; ++it) {
        const int r0 = it * 32 + rp * 2;
        float4 v0 = va[it][0], v1 = va[it][1];
        bf16 a0 = (bf16)v0.x, a1 = (bf16)v0.y, a2 = (bf16)v0.z, a3 = (bf16)v0.w;
        bf16 b0 = (bf16)v1.x, b1 = (bf16)v1.y, b2 = (bf16)v1.z, b3 = (bf16)v1.w;
        bf16x4 p0 = { a0, a1, a2, a3 }, p1 = { b0, b1, b2, b3 };
        *(bf16x4*)(Xbbh + (size_t)r0 * HD + c4)       = p0;
        *(bf16x4*)(Xbbh + (size_t)(r0 + 1) * HD + c4) = p1;
        const int w = it * 16 + rp;        // s-pair index 0..31
        sT[(c4 + 0) * 33 + w] = pack2(a0, b0);
        sT[(c4 + 1) * 33 + w] = pack2(a1, b1);
        sT[(c4 + 2) * 33 + w] = pack2(a2, b2);
        sT[(c4 + 3) * 33 + w] = pack2(a3, b3);
    }
    __syncthreads();

    // ---- Phase B: 4 b32 LDS reads -> one 16B global store, x2 ----
    bf16* XTbh = XT + (size_t)bh * HD * S_LEN + (size_t)st64 * 64;
    #pragma unroll
    for (int i = 0; i < 2; ++i) {
        const int c  = i * 256 + tid;
        const int dd = c >> 3;             // 0..63
        const int wg = (c & 7) * 4;        // u32 index along s-pairs (0..28)
        u32x4 qv = { sT[dd * 33 + wg],     sT[dd * 33 + wg + 1],
                     sT[dd * 33 + wg + 2], sT[dd * 33 + wg + 3] };
        *(u32x4*)((char*)(XTbh + (size_t)dd * S_LEN) + (size_t)wg * 4) = qv;
    }
}

// ---------------------------------------------------------------------------
// attn: one block per (bh, 256-q tile); 8 waves x 32 q rows/wave.
// T15 pipeline: S(t) overlaps softmax+PV(t-1). Grid dim3(64,8): XCD-local.
// ---------------------------------------------------------------------------
__global__ __launch_bounds__(512, 4)
void attn_kernel(const bf16* __restrict__ Xb, const bf16* __restrict__ XT,
                 const bf16* __restrict__ Mw, const float* __restrict__ Uv,
                 float* __restrict__ out) {
    // 4 staging buffers: buf i = smem + i*16384 (sXk 8KB, then sXkT 8KB)
    __shared__ __align__(16) char smem[4 * 16384 + 1024];
    float (*sL)[32] = (float(*)[32])(smem + 65536);   // per-wave 1/l

    const int tid  = threadIdx.x;
    const int wave = tid >> 6, lane = tid & 63;
    const int hi   = lane >> 5, q32 = lane & 31;
    const int wbase = wave * 32;           // this wave's 32 q rows (block-local)
    const int bh = blockIdx.x, qt = blockIdx.y;
    const int q0 = qt * QT;

    const char* Xbh  = (const char*)(Xb + (size_t)bh * S_LEN * HD);   // 128B rows
    const char* XTbh = (const char*)(XT + (size_t)bh * HD * S_LEN);   // 4096B rows

    const floatx16 z16 = {0,0,0,0, 0,0,0,0, 0,0,0,0, 0,0,0,0};

    // ---- prologue: T^T = M'. Xq^T + u' (C col = q -> T rows lane-local) ----
    bf16x8 Tfrag[4];
    {
        floatx16 Tacc[2];                  // [ddt]; C: row=dd, col=q
        #pragma unroll
        for (int ddt = 0; ddt < 2; ++ddt) Tacc[ddt] = z16;

        #pragma unroll
        for (int kc = 0; kc < 4; ++kc) {
            bf16x8 am[2];
            #pragma unroll
            for (int ddt = 0; ddt < 2; ++ddt)
                am[ddt] = *(const bf16x8*)(Mw + (ddt * 32 + q32) * 64 + kc * 16 + hi * 8);
            bf16x8 xq = *(const bf16x8*)(Xbh +
                (size_t)(q0 + wbase + q32) * 128 + kc * 32 + hi * 16);
            #pragma unroll
            for (int ddt = 0; ddt < 2; ++ddt)
                Tacc[ddt] = mfma32(am[ddt], xq, Tacc[ddt]);
        }
        // u' fold along dd (rows of C): dd = ddt*32 + 8*(r>>2) + 4*hi + (r&3)
        #pragma unroll
        for (int ddt = 0; ddt < 2; ++ddt)
            #pragma unroll
            for (int r = 0; r < 16; ++r)
                Tacc[ddt][r] += Uv[ddt * 32 + 8 * (r >> 2) + 4 * hi + (r & 3)];
        // C -> B-frag conversion (cvt_pk + permlane32_swap), in-register
        #pragma unroll
        for (int kc = 0; kc < 4; ++kc) {
            const int ddt = kc >> 1, a4 = 8 * (kc & 1);
            u32 X  = cvtpk(Tacc[ddt][a4 + 0], Tacc[ddt][a4 + 1]);
            u32 Y  = cvtpk(Tacc[ddt][a4 + 4], Tacc[ddt][a4 + 5]);
            swap32(X, Y);
            u32 X2 = cvtpk(Tacc[ddt][a4 + 2], Tacc[ddt][a4 + 3]);
            u32 Y2 = cvtpk(Tacc[ddt][a4 + 6], Tacc[ddt][a4 + 7]);
            swap32(X2, Y2);
            u32x4 w = { X, X2, Y, Y2 };
            Tfrag[kc] = __builtin_bit_cast(bf16x8, w);
        }
    }

    // ---- async staging into buffer idx (conflict-free XOR swizzle) ----
    // 8 waves: wave w stages rows w*8..w*8+7 of Xk and of XkT (1KB each).
    auto stage = [&](int kt, int idx) {
        char* base = smem + idx * 16384;
        const int k0 = kt * KT2;
        {
            int s = wave * 8 + (lane >> 3);
            const char* g = Xbh + (size_t)(k0 + s) * 128 + (((lane & 7) ^ (s & 7)) << 4);
            ldsdma16(base + wave * 1024, g);
        }
        {
            int dd = wave * 8 + (lane >> 3);
            const char* g = XTbh + (size_t)dd * 4096 + (size_t)k0 * 2 + (((lane & 7) ^ (dd & 7)) << 4);
            ldsdma16(base + 8192 + wave * 1024, g);
        }
    };

    floatx16 Oacc[2];                      // [nt]; C: row=q, col=dd
    float l_run = 0.f;                     // per-lane: q = q32
    #pragma unroll
    for (int nt = 0; nt < 2; ++nt) Oacc[nt] = z16;

    // ---- S-issue: S^T(kt) = Xk.T^T from buf idx; first kc takes z16 ----
    auto Sissue = [&](floatx16 (&S)[2], int idx) {
        const char* xkb = (const char*)smem + idx * 16384;
        __builtin_amdgcn_s_setprio(1);
        #pragma unroll
        for (int kc = 0; kc < 4; ++kc) {
            bf16x8 ak[2];
            #pragma unroll
            for (int k32t = 0; k32t < 2; ++k32t)
                ak[k32t] = *(const bf16x8*)(xkb + (k32t * 32 + q32) * 128 +
                                            (((2 * kc + hi) ^ (q32 & 7)) << 4));
            #pragma unroll
            for (int k32t = 0; k32t < 2; ++k32t)
                S[k32t] = mfma32(ak[k32t], Tfrag[kc], kc == 0 ? z16 : S[k32t]);
        }
        __builtin_amdgcn_s_setprio(0);
    };

    // ---- fin: softmax (in-register) + PV of a finished S, vs buf idx ----
    auto fin = [&](floatx16 (&S)[2], int idx) {
        #pragma unroll
        for (int k32t = 0; k32t < 2; ++k32t)
            #pragma unroll
            for (int r = 0; r < 16; ++r) {
                float pe = __builtin_amdgcn_exp2f(S[k32t][r]);
                S[k32t][r] = pe;
                l_run += pe;
            }
        const char* xktb = (const char*)smem + idx * 16384 + 8192;
        #pragma unroll
        for (int s = 0; s < 4; ++s) {
            const int k32t = s >> 1, a4 = 8 * (s & 1);
            u32 X  = cvtpk(S[k32t][a4 + 0], S[k32t][a4 + 1]);
            u32 Y  = cvtpk(S[k32t][a4 + 4], S[k32t][a4 + 5]);
            swap32(X, Y);
            u32 X2 = cvtpk(S[k32t][a4 + 2], S[k32t][a4 + 3]);
            u32 Y2 = cvtpk(S[k32t][a4 + 6], S[k32t][a4 + 7]);
            swap32(X2, Y2);
            u32x4 w = { X, X2, Y, Y2 };
            bf16x8 pa = __builtin_bit_cast(bf16x8, w);
            __builtin_amdgcn_s_setprio(1);
            #pragma unroll
            for (int nt = 0; nt < 2; ++nt) {
                const int dd = nt * 32 + q32;
                bf16x8 bb = *(const bf16x8*)(xktb + dd * 128 +
                                             (((2 * s + hi) ^ (q32 & 7)) << 4));
                Oacc[nt] = mfma32(pa, bb, Oacc[nt]);
            }
            __builtin_amdgcn_s_setprio(0);
        }
    };

    floatx16 SA[2], SB[2];                 // double Sacc for the pipeline

    // ---- pipelined K loop (r12 scheme, mt=1 geometry) ----
    // slot t: vmcnt(2); barrier; stage(t+2); S(t)->cur; fin(t-1)<-prev.
    // Tile->buffer: t & 3. Even tiles in SA, odd in SB.
    stage(0, 0);
    stage(1, 1);
    VMCNT_WAIT(2);                         // stage(0) done; stage(1) in flight
    BARRIER();
    stage(2, 2);
    Sissue(SA, 0);                         // S(0)

    for (int t = 1; t < NKT - 2; t += 2) { // slots 1..30 (15 iterations)
        // slot t (odd): cur=SB, prev=SA
        VMCNT_WAIT(2);
        BARRIER();
        stage(t + 2, (t + 2) & 3);         // t+2 <= 31 here
        Sissue(SB, t & 3);
        fin(SA, (t - 1) & 3);
        // slot t+1 (even): cur=SA, prev=SB
        VMCNT_WAIT(2);
        BARRIER();
        if (t + 3 < NKT) stage(t + 3, (t + 3) & 3);
        Sissue(SA, (t + 1) & 3);
        fin(SB, t & 3);
    }
    // slot 31 (odd): last stage must be fully drained -> vmcnt(0)
    VMCNT_WAIT(0);
    BARRIER();
    Sissue(SB, (NKT - 1) & 3);
    fin(SA, (NKT - 2) & 3);
    fin(SB, (NKT - 1) & 3);

    // ---- epilogue: combine l halves, broadcast 1/l via tiny LDS, store ----
    {
        float lt = l_run + __shfl_xor(l_run, 32);
        if (hi == 0) sL[wave][q32] = 1.0f / lt;
    }
    __syncthreads();

    float* outb = out + ((size_t)bh * S_LEN + q0) * HD;
    #pragma unroll
    for (int r = 0; r < 16; ++r) {
        const int qlocal = 8 * (r >> 2) + 4 * hi + (r & 3);
        const float rl = sL[wave][qlocal];
        const int qrow = wbase + qlocal;
        #pragma unroll
        for (int nt = 0; nt < 2; ++nt)
            outb[(size_t)qrow * HD + nt * 32 + q32] = Oacc[nt][r] * rl;
    }
}

extern "C" void kernel_launch(void* const* d_in, const int* in_sizes, int n_in,
                              void* d_out, int out_size, void* d_ws, size_t ws_size,
                              hipStream_t stream) {
    const float* x    = (const float*)d_in[0];
    // d_in[1] (mask): per-(b,q) additive constant across keys -> softmax no-op.
    const float* W    = (const float*)d_in[2];
    const float* bvec = (const float*)d_in[3];

    bf16*  Mws = (bf16*)d_ws;                         // 8192 B
    float* Uws = (float*)((char*)d_ws + 8192);        // 256 B
    bf16*  Xbws = (bf16*)((char*)d_ws + 540672);      // 16777216 B
    bf16*  XTws = (bf16*)((char*)d_ws + 17317888);    // 16777216 B

    prex_kernel<<<dim3(33, 16, 4), dim3(256), 0, stream>>>(x, W, bvec,
                                                           Xbws, XTws, Uws, Mws);
    attn_kernel<<<dim3(64, 8, 1),  dim3(512), 0, stream>>>(Xbws, XTws, Mws, Uws,
                                                           (float*)d_out);
}

// Round 11
// 188.583 us; speedup vs baseline: 1.1399x; 1.1399x over previous
//
#include <hip/hip_runtime.h>
#include <math.h>

// ---------------------------------------------------------------------------
// MultiHeadAttention, B=4 H=16 S=2048 D=1024 (d=64), fp32 in/out.
//
// Algebra (verified r1-r10): mask softmax-shift-invariant -> dropped.
// q==k (shared Dense). M = W W^T symmetric, u = W b.
// S_ij = (x_i M + u).x_j (mod per-row const); u folds into T along dd.
// Second matmul uses x_h itself. No max-sub needed (scores O(+-1)).
//
// r17: r15 attn (82.5us verified) + issue-bound micro-opts. CLOSED paths:
//  * T15 double-S pipeline: spills/scratch 2-for-2 (r12: VGPR spill 276MB
//    WRITE; r16: SGPR 112 + 161MB FETCH scratch path). Never again.
//  * occupancy (r7/r13: 2x waves, flat), memory (r2: FETCH -7x, flat),
//    PV-from-global (r14: VMEM << DS for 1KB/wave loads, 2.2x regression).
// r15 counters: MfmaUtil 36.7 + VALUBusy 46 = 83% issue-port utilization,
// HBM 8% -> issue-bound. This round cuts VALU ops:
//  1. Sacc zero-init deleted (first-kc MFMA takes z16 as C; r16-verified).
//  2. aoff[kc] = q32*128 + slot16[kc] hoisted; all 16 LDS reads/kt become
//     base + aoff + compile-time imm (S and PV share the same aoff set).
//  3. l_run -> 4 partial sums (dep chain 32 -> 8), reduced in epilogue.
//  4. stage(kt+1) issued AFTER the S-MFMA cluster (MFMA starts at barrier).
// prex = r15 (exhausted; residual ~85us is harness reset cost, r9-proven).
// Kernel boundary prex|attn = cross-XCD flush (r11 raced; G16).
// Grid dim3(64 bh, 8 qt): XCD-local slices (r8: FETCH -7x).
// ---------------------------------------------------------------------------

#define S_LEN   2048
#define D_MODEL 1024
#define HD      64
#define NHEAD   16
#define QT      256
#define KT2     64
#define NKT     (S_LEN / KT2)   // 32

typedef __bf16 bf16;
typedef __bf16 bf16x8 __attribute__((ext_vector_type(8)));
typedef __bf16 bf16x4 __attribute__((ext_vector_type(4)));
typedef __bf16 bf16x2 __attribute__((ext_vector_type(2)));
typedef float  floatx16 __attribute__((ext_vector_type(16)));
typedef unsigned int u32;
typedef u32 u32x4 __attribute__((ext_vector_type(4)));

#define SCALE 0.02254211001389005324f   // log2(e)/64

__device__ __forceinline__ floatx16 mfma32(bf16x8 a, bf16x8 b, floatx16 c) {
    return __builtin_amdgcn_mfma_f32_32x32x16_bf16(a, b, c, 0, 0, 0);
}

__device__ __forceinline__ void ldsdma16(void* lds_base, const void* gsrc) {
    __builtin_amdgcn_global_load_lds(
        (const __attribute__((address_space(1))) u32*)gsrc,
        (__attribute__((address_space(3))) u32*)lds_base, 16, 0, 0);
}

__device__ __forceinline__ u32 pack2(bf16 lo, bf16 hi) {
    bf16x2 p = { lo, hi };
    return __builtin_bit_cast(u32, p);
}

__device__ __forceinline__ u32 cvtpk(float lo, float hi) {
    u32 r;
    asm("v_cvt_pk_bf16_f32 %0, %1, %2" : "=v"(r) : "v"(lo), "v"(hi));
    return r;
}
// swaps: x[32:63] <-> y[0:31].  After: x = {x.lo, y.lo}, y = {x.hi, y.hi}.
__device__ __forceinline__ void swap32(u32& x, u32& y) {
    asm("v_permlane32_swap_b32 %0, %1" : "+v"(x), "+v"(y));
}

// ---------------------------------------------------------------------------
// prex (r15, verified): st64<32 -> Xb/XT for one 64-row s-tile;
// st64==32 (h==0,b==0) -> M' = W W^T * SCALE and u' = W b * SCALE.
// ---------------------------------------------------------------------------
__global__ __launch_bounds__(256)
void prex_kernel(const float* __restrict__ x, const float* __restrict__ W,
                 const float* __restrict__ bvec,
                 bf16* __restrict__ Xb, bf16* __restrict__ XT,
                 float* __restrict__ Uout, bf16* __restrict__ Mout) {
    __shared__ __align__(16) char smem[16896];
    u32*   sT = (u32*)smem;               // [64 dd][33] u32 (s-pairs), 8448 B
    float* Wp = (float*)smem;             // prep overlay: [64][65] fp32, 16640 B
    float* bs = (float*)(smem + 16640);   // prep overlay: 64 fp32, 256 B

    const int tid = threadIdx.x;
    const int st64 = blockIdx.x, h = blockIdx.y, b = blockIdx.z;

    if (st64 == 32) {                      // fused prep block
        if (h != 0 || b != 0) return;
        for (int i = tid; i < 4096; i += 256) Wp[(i >> 6) * 65 + (i & 63)] = W[i];
        if (tid < 64) bs[tid] = bvec[tid];
        __syncthreads();
        for (int e = tid; e < 4096; e += 256) {
            int i = e >> 6, j = e & 63;
            float acc = 0.f;
            #pragma unroll 8
            for (int c = 0; c < 64; ++c) acc += Wp[i * 65 + c] * Wp[j * 65 + c];
            Mout[e] = (bf16)(acc * SCALE);
        }
        if (tid < 64) {
            float acc = 0.f;
            #pragma unroll 8
            for (int c = 0; c < 64; ++c) acc += Wp[tid * 65 + c] * bs[c];
            Uout[tid] = acc * SCALE;
        }
        return;
    }

    const int bh = b * NHEAD + h;
    const float* xbh = x + (size_t)b * S_LEN * D_MODEL +
                       (size_t)st64 * 64 * D_MODEL + h * HD;
    bf16* Xbbh = Xb + ((size_t)bh * S_LEN + st64 * 64) * HD;

    const int t  = tid & 15;       // column group: c4 = 4t (floats)
    const int rp = tid >> 4;       // row-pair index within a 32-row slab
    const int c4 = t * 4;

    // ---- Phase A: ALL loads first (4x float4 in flight), then convert ----
    float4 va[2][2];
    #pragma unroll
    for (int it = 0; it < 2; ++it)
        #pragma unroll
        for (int k = 0; k < 2; ++k)
            va[it][k] = *(const float4*)(xbh +
                (size_t)(it * 32 + rp * 2 + k) * D_MODEL + c4);

    #pragma unroll
    for (int it = 0; it < 2; ++it) {
        const int r0 = it * 32 + rp * 2;
        float4 v0 = va[it][0], v1 = va[it][1];
        bf16 a0 = (bf16)v0.x, a1 = (bf16)v0.y, a2 = (bf16)v0.z, a3 = (bf16)v0.w;
        bf16 b0 = (bf16)v1.x, b1 = (bf16)v1.y, b2 = (bf16)v1.z, b3 = (bf16)v1.w;
        bf16x4 p0 = { a0, a1, a2, a3 }, p1 = { b0, b1, b2, b3 };
        *(bf16x4*)(Xbbh + (size_t)r0 * HD + c4)       = p0;
        *(bf16x4*)(Xbbh + (size_t)(r0 + 1) * HD + c4) = p1;
        const int w = it * 16 + rp;        // s-pair index 0..31
        sT[(c4 + 0) * 33 + w] = pack2(a0, b0);
        sT[(c4 + 1) * 33 + w] = pack2(a1, b1);
        sT[(c4 + 2) * 33 + w] = pack2(a2, b2);
        sT[(c4 + 3) * 33 + w] = pack2(a3, b3);
    }
    __syncthreads();

    // ---- Phase B: 4 b32 LDS reads -> one 16B global store, x2 ----
    bf16* XTbh = XT + (size_t)bh * HD * S_LEN + (size_t)st64 * 64;
    #pragma unroll
    for (int i = 0; i < 2; ++i) {
        const int c  = i * 256 + tid;
        const int dd = c >> 3;             // 0..63
        const int wg = (c & 7) * 4;        // u32 index along s-pairs (0..28)
        u32x4 qv = { sT[dd * 33 + wg],     sT[dd * 33 + wg + 1],
                     sT[dd * 33 + wg + 2], sT[dd * 33 + wg + 3] };
        *(u32x4*)((char*)(XTbh + (size_t)dd * S_LEN) + (size_t)wg * 4) = qv;
    }
}

// ---------------------------------------------------------------------------
// attn: one block per (bh, 256-q tile); 8 waves x 32 q rows/wave.
// Grid dim3(64,8): bh fastest -> XCD-local slices (verified r8: FETCH -7x).
// ---------------------------------------------------------------------------
__global__ __launch_bounds__(512, 4)
void attn_kernel(const bf16* __restrict__ Xb, const bf16* __restrict__ XT,
                 const bf16* __restrict__ Mw, const float* __restrict__ Uv,
                 float* __restrict__ out) {
    __shared__ bf16  sXk [2 * KT2 * HD];   // 16KB, swizzled 128B rows [key][dd]
    __shared__ bf16  sXkT[2 * HD * KT2];   // 16KB, swizzled 128B rows [dd][key]
    __shared__ float sL[8][32];            // 1KB: per-wave 1/l for epilogue

    const int tid  = threadIdx.x;
    const int wave = tid >> 6, lane = tid & 63;
    const int hi   = lane >> 5, q32 = lane & 31;
    const int wbase = wave * 32;           // this wave's 32 q rows (block-local)
    const int bh = blockIdx.x, qt = blockIdx.y;
    const int q0 = qt * QT;

    const char* Xbh  = (const char*)(Xb + (size_t)bh * S_LEN * HD);   // 128B rows
    const char* XTbh = (const char*)(XT + (size_t)bh * HD * S_LEN);   // 4096B rows

    const floatx16 z16 = {0,0,0,0, 0,0,0,0, 0,0,0,0, 0,0,0,0};

    // Hoisted per-lane LDS byte offsets: S read (k32t,kc) at aoff[kc]+k32t*4096;
    // PV read (nt,s) at aoff[s]+nt*4096 (identical slot-swizzle term set).
    int aoff[4];
    #pragma unroll
    for (int kc = 0; kc < 4; ++kc)
        aoff[kc] = q32 * 128 + (((((kc << 1) | hi)) ^ (q32 & 7)) << 4);

    // ---- prologue: T^T = M'. Xq^T + u' (C col = q -> T rows lane-local) ----
    bf16x8 Tfrag[4];
    {
        floatx16 Tacc[2];                  // [ddt]; C: row=dd, col=q
        #pragma unroll
        for (int ddt = 0; ddt < 2; ++ddt) Tacc[ddt] = z16;

        #pragma unroll
        for (int kc = 0; kc < 4; ++kc) {
            bf16x8 am[2];
            #pragma unroll
            for (int ddt = 0; ddt < 2; ++ddt)
                am[ddt] = *(const bf16x8*)(Mw + (ddt * 32 + q32) * 64 + kc * 16 + hi * 8);
            bf16x8 xq = *(const bf16x8*)(Xbh +
                (size_t)(q0 + wbase + q32) * 128 + kc * 32 + hi * 16);
            #pragma unroll
            for (int ddt = 0; ddt < 2; ++ddt)
                Tacc[ddt] = mfma32(am[ddt], xq, Tacc[ddt]);
        }
        // u' fold along dd (rows of C): dd = ddt*32 + 8*(r>>2) + 4*hi + (r&3)
        #pragma unroll
        for (int ddt = 0; ddt < 2; ++ddt)
            #pragma unroll
            for (int r = 0; r < 16; ++r)
                Tacc[ddt][r] += Uv[ddt * 32 + 8 * (r >> 2) + 4 * hi + (r & 3)];
        // C -> B-frag conversion (cvt_pk + permlane32_swap), in-register
        #pragma unroll
        for (int kc = 0; kc < 4; ++kc) {
            const int ddt = kc >> 1, a4 = 8 * (kc & 1);
            u32 X  = cvtpk(Tacc[ddt][a4 + 0], Tacc[ddt][a4 + 1]);
            u32 Y  = cvtpk(Tacc[ddt][a4 + 4], Tacc[ddt][a4 + 5]);
            swap32(X, Y);
            u32 X2 = cvtpk(Tacc[ddt][a4 + 2], Tacc[ddt][a4 + 3]);
            u32 Y2 = cvtpk(Tacc[ddt][a4 + 6], Tacc[ddt][a4 + 7]);
            swap32(X2, Y2);
            u32x4 w = { X, X2, Y, Y2 };
            Tfrag[kc] = __builtin_bit_cast(bf16x8, w);
        }
    }

    // ---- async staging (conflict-free XOR swizzle, verified r3/r4) ----
    // 8 waves: wave w stages rows w*8..w*8+7 of Xk and of XkT (1KB each).
    auto stage = [&](int kt, int par) {
        const int k0 = kt * KT2;
        {
            int s = wave * 8 + (lane >> 3);
            const char* g = Xbh + (size_t)(k0 + s) * 128 + (((lane & 7) ^ (s & 7)) << 4);
            ldsdma16((char*)sXk + par * 8192 + wave * 1024, g);
        }
        {
            int dd = wave * 8 + (lane >> 3);
            const char* g = XTbh + (size_t)dd * 4096 + (size_t)k0 * 2 + (((lane & 7) ^ (dd & 7)) << 4);
            ldsdma16((char*)sXkT + par * 8192 + wave * 1024, g);
        }
    };

    floatx16 Oacc[2];                      // [nt]; C: row=q, col=dd
    float l4[4] = {0.f, 0.f, 0.f, 0.f};    // partial l sums (dep chain 8)
    #pragma unroll
    for (int nt = 0; nt < 2; ++nt) Oacc[nt] = z16;

    stage(0, 0);

    auto body = [&](int kt, const int par) {
        __syncthreads();               // drains stage(kt) + prior-buffer readers

        // ---- S^T = Xk . T^T : C[row=key][col=q]; first kc takes z16 ----
        const char* xkb = (const char*)sXk + par * 8192;
        floatx16 Sacc[2];              // [k32t]
        __builtin_amdgcn_s_setprio(1);
        #pragma unroll
        for (int kc = 0; kc < 4; ++kc) {
            bf16x8 ak[2];
            #pragma unroll
            for (int k32t = 0; k32t < 2; ++k32t)
                ak[k32t] = *(const bf16x8*)(xkb + aoff[kc] + k32t * 4096);
            #pragma unroll
            for (int k32t = 0; k32t < 2; ++k32t)
                Sacc[k32t] = mfma32(ak[k32t], Tfrag[kc],
                                    kc == 0 ? z16 : Sacc[k32t]);
        }
        __builtin_amdgcn_s_setprio(0);

        // next-tile staging issued under the S-MFMA pipe
        if (kt + 1 < NKT) stage(kt + 1, par ^ 1);

        // ---- softmax numerators fully in-register (4 partial l chains) ----
        #pragma unroll
        for (int k32t = 0; k32t < 2; ++k32t)
            #pragma unroll
            for (int r = 0; r < 16; ++r) {
                float pe = __builtin_amdgcn_exp2f(Sacc[k32t][r]);
                Sacc[k32t][r] = pe;
                l4[r & 3] += pe;
            }

        // ---- PV: P->A-frags via cvt_pk+permlane, B from sXkT ----
        const char* xktb = (const char*)sXkT + par * 8192;
        #pragma unroll
        for (int s = 0; s < 4; ++s) {
            const int k32t = s >> 1, a4 = 8 * (s & 1);
            u32 X  = cvtpk(Sacc[k32t][a4 + 0], Sacc[k32t][a4 + 1]);
            u32 Y  = cvtpk(Sacc[k32t][a4 + 4], Sacc[k32t][a4 + 5]);
            swap32(X, Y);
            u32 X2 = cvtpk(Sacc[k32t][a4 + 2], Sacc[k32t][a4 + 3]);
            u32 Y2 = cvtpk(Sacc[k32t][a4 + 6], Sacc[k32t][a4 + 7]);
            swap32(X2, Y2);
            u32x4 w = { X, X2, Y, Y2 };
            bf16x8 pa = __builtin_bit_cast(bf16x8, w);
            __builtin_amdgcn_s_setprio(1);
            #pragma unroll
            for (int nt = 0; nt < 2; ++nt) {
                bf16x8 bb = *(const bf16x8*)(xktb + aoff[s] + nt * 4096);
                Oacc[nt] = mfma32(pa, bb, Oacc[nt]);
            }
            __builtin_amdgcn_s_setprio(0);
        }
    };

    for (int kt = 0; kt < NKT; kt += 2) {
        body(kt, 0);
        body(kt + 1, 1);
    }

    // ---- epilogue: combine l partials + halves, broadcast 1/l, store ----
    {
        float l_run = (l4[0] + l4[1]) + (l4[2] + l4[3]);
        float lt = l_run + __shfl_xor(l_run, 32);
        if (hi == 0) sL[wave][q32] = 1.0f / lt;
    }
    __syncthreads();

    float* outb = out + ((size_t)bh * S_LEN + q0) * HD;
    #pragma unroll
    for (int r = 0; r < 16; ++r) {
        const int qlocal = 8 * (r >> 2) + 4 * hi + (r & 3);
        const float rl = sL[wave][qlocal];
        const int qrow = wbase + qlocal;
        #pragma unroll
        for (int nt = 0; nt < 2; ++nt)
            outb[(size_t)qrow * HD + nt * 32 + q32] = Oacc[nt][r] * rl;
    }
}

extern "C" void kernel_launch(void* const* d_in, const int* in_sizes, int n_in,
                              void* d_out, int out_size, void* d_ws, size_t ws_size,
                              hipStream_t stream) {
    const float* x    = (const float*)d_in[0];
    // d_in[1] (mask): per-(b,q) additive constant across keys -> softmax no-op.
    const float* W    = (const float*)d_in[2];
    const float* bvec = (const float*)d_in[3];

    bf16*  Mws = (bf16*)d_ws;                         // 8192 B
    float* Uws = (float*)((char*)d_ws + 8192);        // 256 B
    bf16*  Xbws = (bf16*)((char*)d_ws + 540672);      // 16777216 B
    bf16*  XTws = (bf16*)((char*)d_ws + 17317888);    // 16777216 B

    prex_kernel<<<dim3(33, 16, 4), dim3(256), 0, stream>>>(x, W, bvec,
                                                           Xbws, XTws, Uws, Mws);
    attn_kernel<<<dim3(64, 8, 1),  dim3(512), 0, stream>>>(Xbws, XTws, Mws, Uws,
                                                           (float*)d_out);
}

// Round 12
// 172.992 us; speedup vs baseline: 1.2426x; 1.0901x over previous
//
#include <hip/hip_runtime.h>
#include <math.h>

// ---------------------------------------------------------------------------
// MultiHeadAttention, B=4 H=16 S=2048 D=1024 (d=64), fp32 in/out.
//
// Algebra (verified r1-r10): mask softmax-shift-invariant -> dropped.
// q==k (shared Dense). M = W W^T symmetric, u = W b.
// S_ij = (x_i M + u).x_j (mod per-row const); u folds into T along dd.
// Second matmul uses x_h itself. No max-sub needed (scores O(+-1)).
//
// r18 = r15 (attn 82.5us verified) + ONLY two pure op-reductions:
//  1. Sacc zero-init deleted (first-kc MFMA takes z16 as C).
//  2. l_run -> 4 partials (exp2-add dep chain 32 -> 8), folded in epilogue.
// Stage placement / addressing / swizzle byte-identical to r15. r17 taught:
// timing-sensitive reorder (stage after S-MFMA, aoff hoist) broke L2 pacing
// (FETCH 20->45MB, attn 103us) — reverted.
// CLOSED paths (do not retry): T15 double-S pipeline (spills 2-for-2:
// r12 VGPR/276MB WRITE, r16 scratch/161MB FETCH); occupancy (r7/r13 flat);
// PV-from-global (r14, 2.2x); cooperative fusion (r11 races, G16);
// prex rewrites (r7->r9: residual ~85us is harness-fixed).
// Grid dim3(64 bh, 8 qt): XCD-local slices (r8: FETCH -7x).
// ---------------------------------------------------------------------------

#define S_LEN   2048
#define D_MODEL 1024
#define HD      64
#define NHEAD   16
#define QT      256
#define KT2     64
#define NKT     (S_LEN / KT2)   // 32

typedef __bf16 bf16;
typedef __bf16 bf16x8 __attribute__((ext_vector_type(8)));
typedef __bf16 bf16x4 __attribute__((ext_vector_type(4)));
typedef __bf16 bf16x2 __attribute__((ext_vector_type(2)));
typedef float  floatx16 __attribute__((ext_vector_type(16)));
typedef unsigned int u32;
typedef u32 u32x4 __attribute__((ext_vector_type(4)));

#define SCALE 0.02254211001389005324f   // log2(e)/64

__device__ __forceinline__ floatx16 mfma32(bf16x8 a, bf16x8 b, floatx16 c) {
    return __builtin_amdgcn_mfma_f32_32x32x16_bf16(a, b, c, 0, 0, 0);
}

__device__ __forceinline__ void ldsdma16(void* lds_base, const void* gsrc) {
    __builtin_amdgcn_global_load_lds(
        (const __attribute__((address_space(1))) u32*)gsrc,
        (__attribute__((address_space(3))) u32*)lds_base, 16, 0, 0);
}

__device__ __forceinline__ u32 pack2(bf16 lo, bf16 hi) {
    bf16x2 p = { lo, hi };
    return __builtin_bit_cast(u32, p);
}

__device__ __forceinline__ u32 cvtpk(float lo, float hi) {
    u32 r;
    asm("v_cvt_pk_bf16_f32 %0, %1, %2" : "=v"(r) : "v"(lo), "v"(hi));
    return r;
}
// swaps: x[32:63] <-> y[0:31].  After: x = {x.lo, y.lo}, y = {x.hi, y.hi}.
__device__ __forceinline__ void swap32(u32& x, u32& y) {
    asm("v_permlane32_swap_b32 %0, %1" : "+v"(x), "+v"(y));
}

// ---------------------------------------------------------------------------
// prex (r15, verified): st64<32 -> Xb/XT for one 64-row s-tile;
// st64==32 (h==0,b==0) -> M' = W W^T * SCALE and u' = W b * SCALE.
// ---------------------------------------------------------------------------
__global__ __launch_bounds__(256)
void prex_kernel(const float* __restrict__ x, const float* __restrict__ W,
                 const float* __restrict__ bvec,
                 bf16* __restrict__ Xb, bf16* __restrict__ XT,
                 float* __restrict__ Uout, bf16* __restrict__ Mout) {
    __shared__ __align__(16) char smem[16896];
    u32*   sT = (u32*)smem;               // [64 dd][33] u32 (s-pairs), 8448 B
    float* Wp = (float*)smem;             // prep overlay: [64][65] fp32, 16640 B
    float* bs = (float*)(smem + 16640);   // prep overlay: 64 fp32, 256 B

    const int tid = threadIdx.x;
    const int st64 = blockIdx.x, h = blockIdx.y, b = blockIdx.z;

    if (st64 == 32) {                      // fused prep block
        if (h != 0 || b != 0) return;
        for (int i = tid; i < 4096; i += 256) Wp[(i >> 6) * 65 + (i & 63)] = W[i];
        if (tid < 64) bs[tid] = bvec[tid];
        __syncthreads();
        for (int e = tid; e < 4096; e += 256) {
            int i = e >> 6, j = e & 63;
            float acc = 0.f;
            #pragma unroll 8
            for (int c = 0; c < 64; ++c) acc += Wp[i * 65 + c] * Wp[j * 65 + c];
            Mout[e] = (bf16)(acc * SCALE);
        }
        if (tid < 64) {
            float acc = 0.f;
            #pragma unroll 8
            for (int c = 0; c < 64; ++c) acc += Wp[tid * 65 + c] * bs[c];
            Uout[tid] = acc * SCALE;
        }
        return;
    }

    const int bh = b * NHEAD + h;
    const float* xbh = x + (size_t)b * S_LEN * D_MODEL +
                       (size_t)st64 * 64 * D_MODEL + h * HD;
    bf16* Xbbh = Xb + ((size_t)bh * S_LEN + st64 * 64) * HD;

    const int t  = tid & 15;       // column group: c4 = 4t (floats)
    const int rp = tid >> 4;       // row-pair index within a 32-row slab
    const int c4 = t * 4;

    // ---- Phase A: ALL loads first (4x float4 in flight), then convert ----
    float4 va[2][2];
    #pragma unroll
    for (int it = 0; it < 2; ++it)
        #pragma unroll
        for (int k = 0; k < 2; ++k)
            va[it][k] = *(const float4*)(xbh +
                (size_t)(it * 32 + rp * 2 + k) * D_MODEL + c4);

    #pragma unroll
    for (int it = 0; it < 2; ++it) {
        const int r0 = it * 32 + rp * 2;
        float4 v0 = va[it][0], v1 = va[it][1];
        bf16 a0 = (bf16)v0.x, a1 = (bf16)v0.y, a2 = (bf16)v0.z, a3 = (bf16)v0.w;
        bf16 b0 = (bf16)v1.x, b1 = (bf16)v1.y, b2 = (bf16)v1.z, b3 = (bf16)v1.w;
        bf16x4 p0 = { a0, a1, a2, a3 }, p1 = { b0, b1, b2, b3 };
        *(bf16x4*)(Xbbh + (size_t)r0 * HD + c4)       = p0;
        *(bf16x4*)(Xbbh + (size_t)(r0 + 1) * HD + c4) = p1;
        const int w = it * 16 + rp;        // s-pair index 0..31
        sT[(c4 + 0) * 33 + w] = pack2(a0, b0);
        sT[(c4 + 1) * 33 + w] = pack2(a1, b1);
        sT[(c4 + 2) * 33 + w] = pack2(a2, b2);
        sT[(c4 + 3) * 33 + w] = pack2(a3, b3);
    }
    __syncthreads();

    // ---- Phase B: 4 b32 LDS reads -> one 16B global store, x2 ----
    bf16* XTbh = XT + (size_t)bh * HD * S_LEN + (size_t)st64 * 64;
    #pragma unroll
    for (int i = 0; i < 2; ++i) {
        const int c  = i * 256 + tid;
        const int dd = c >> 3;             // 0..63
        const int wg = (c & 7) * 4;        // u32 index along s-pairs (0..28)
        u32x4 qv = { sT[dd * 33 + wg],     sT[dd * 33 + wg + 1],
                     sT[dd * 33 + wg + 2], sT[dd * 33 + wg + 3] };
        *(u32x4*)((char*)(XTbh + (size_t)dd * S_LEN) + (size_t)wg * 4) = qv;
    }
}

// ---------------------------------------------------------------------------
// attn (r15 structure): one block per (bh, 256-q tile); 8 waves x 32 q rows.
// Grid dim3(64,8): bh fastest -> XCD-local slices (verified r8: FETCH -7x).
// ---------------------------------------------------------------------------
__global__ __launch_bounds__(512, 4)
void attn_kernel(const bf16* __restrict__ Xb, const bf16* __restrict__ XT,
                 const bf16* __restrict__ Mw, const float* __restrict__ Uv,
                 float* __restrict__ out) {
    __shared__ bf16  sXk [2 * KT2 * HD];   // 16KB, swizzled 128B rows [key][dd]
    __shared__ bf16  sXkT[2 * HD * KT2];   // 16KB, swizzled 128B rows [dd][key]
    __shared__ float sL[8][32];            // 1KB: per-wave 1/l for epilogue

    const int tid  = threadIdx.x;
    const int wave = tid >> 6, lane = tid & 63;
    const int hi   = lane >> 5, q32 = lane & 31;
    const int wbase = wave * 32;           // this wave's 32 q rows (block-local)
    const int bh = blockIdx.x, qt = blockIdx.y;
    const int q0 = qt * QT;

    const char* Xbh  = (const char*)(Xb + (size_t)bh * S_LEN * HD);   // 128B rows
    const char* XTbh = (const char*)(XT + (size_t)bh * HD * S_LEN);   // 4096B rows

    const floatx16 z16 = {0,0,0,0, 0,0,0,0, 0,0,0,0, 0,0,0,0};

    // ---- prologue: T^T = M'. Xq^T + u' (C col = q -> T rows lane-local) ----
    bf16x8 Tfrag[4];
    {
        floatx16 Tacc[2];                  // [ddt]; C: row=dd, col=q
        #pragma unroll
        for (int ddt = 0; ddt < 2; ++ddt) Tacc[ddt] = z16;

        #pragma unroll
        for (int kc = 0; kc < 4; ++kc) {
            bf16x8 am[2];
            #pragma unroll
            for (int ddt = 0; ddt < 2; ++ddt)
                am[ddt] = *(const bf16x8*)(Mw + (ddt * 32 + q32) * 64 + kc * 16 + hi * 8);
            bf16x8 xq = *(const bf16x8*)(Xbh +
                (size_t)(q0 + wbase + q32) * 128 + kc * 32 + hi * 16);
            #pragma unroll
            for (int ddt = 0; ddt < 2; ++ddt)
                Tacc[ddt] = mfma32(am[ddt], xq, Tacc[ddt]);
        }
        // u' fold along dd (rows of C): dd = ddt*32 + 8*(r>>2) + 4*hi + (r&3)
        #pragma unroll
        for (int ddt = 0; ddt < 2; ++ddt)
            #pragma unroll
            for (int r = 0; r < 16; ++r)
                Tacc[ddt][r] += Uv[ddt * 32 + 8 * (r >> 2) + 4 * hi + (r & 3)];
        // C -> B-frag conversion (cvt_pk + permlane32_swap), in-register
        #pragma unroll
        for (int kc = 0; kc < 4; ++kc) {
            const int ddt = kc >> 1, a4 = 8 * (kc & 1);
            u32 X  = cvtpk(Tacc[ddt][a4 + 0], Tacc[ddt][a4 + 1]);
            u32 Y  = cvtpk(Tacc[ddt][a4 + 4], Tacc[ddt][a4 + 5]);
            swap32(X, Y);
            u32 X2 = cvtpk(Tacc[ddt][a4 + 2], Tacc[ddt][a4 + 3]);
            u32 Y2 = cvtpk(Tacc[ddt][a4 + 6], Tacc[ddt][a4 + 7]);
            swap32(X2, Y2);
            u32x4 w = { X, X2, Y, Y2 };
            Tfrag[kc] = __builtin_bit_cast(bf16x8, w);
        }
    }

    // ---- async staging (conflict-free XOR swizzle, verified r3/r4) ----
    // 8 waves: wave w stages rows w*8..w*8+7 of Xk and of XkT (1KB each).
    auto stage = [&](int kt, int par) {
        const int k0 = kt * KT2;
        {
            int s = wave * 8 + (lane >> 3);
            const char* g = Xbh + (size_t)(k0 + s) * 128 + (((lane & 7) ^ (s & 7)) << 4);
            ldsdma16((char*)sXk + par * 8192 + wave * 1024, g);
        }
        {
            int dd = wave * 8 + (lane >> 3);
            const char* g = XTbh + (size_t)dd * 4096 + (size_t)k0 * 2 + (((lane & 7) ^ (dd & 7)) << 4);
            ldsdma16((char*)sXkT + par * 8192 + wave * 1024, g);
        }
    };

    floatx16 Oacc[2];                      // [nt]; C: row=q, col=dd
    float l4[4] = {0.f, 0.f, 0.f, 0.f};    // partial l sums (dep chain 8)
    #pragma unroll
    for (int nt = 0; nt < 2; ++nt) Oacc[nt] = z16;

    stage(0, 0);

    auto body = [&](int kt, const int par) {
        __syncthreads();               // drains stage(kt) + prior-buffer readers
        if (kt + 1 < NKT) stage(kt + 1, par ^ 1);

        // ---- S^T = Xk . T^T : C[row=key][col=q]; first kc takes z16 ----
        const char* xkb = (const char*)sXk + par * 8192;
        floatx16 Sacc[2];              // [k32t]
        __builtin_amdgcn_s_setprio(1);
        #pragma unroll
        for (int kc = 0; kc < 4; ++kc) {
            bf16x8 ak[2];
            #pragma unroll
            for (int k32t = 0; k32t < 2; ++k32t)
                ak[k32t] = *(const bf16x8*)(xkb + (k32t * 32 + q32) * 128 +
                                            (((2 * kc + hi) ^ (q32 & 7)) << 4));
            #pragma unroll
            for (int k32t = 0; k32t < 2; ++k32t)
                Sacc[k32t] = mfma32(ak[k32t], Tfrag[kc],
                                    kc == 0 ? z16 : Sacc[k32t]);
        }
        __builtin_amdgcn_s_setprio(0);

        // ---- softmax numerators fully in-register (4 partial l chains) ----
        #pragma unroll
        for (int k32t = 0; k32t < 2; ++k32t)
            #pragma unroll
            for (int r = 0; r < 16; ++r) {
                float pe = __builtin_amdgcn_exp2f(Sacc[k32t][r]);
                Sacc[k32t][r] = pe;
                l4[r & 3] += pe;
            }

        // ---- PV: P->A-frags via cvt_pk+permlane, B from sXkT ----
        const char* xktb = (const char*)sXkT + par * 8192;
        #pragma unroll
        for (int s = 0; s < 4; ++s) {
            const int k32t = s >> 1, a4 = 8 * (s & 1);
            u32 X  = cvtpk(Sacc[k32t][a4 + 0], Sacc[k32t][a4 + 1]);
            u32 Y  = cvtpk(Sacc[k32t][a4 + 4], Sacc[k32t][a4 + 5]);
            swap32(X, Y);
            u32 X2 = cvtpk(Sacc[k32t][a4 + 2], Sacc[k32t][a4 + 3]);
            u32 Y2 = cvtpk(Sacc[k32t][a4 + 6], Sacc[k32t][a4 + 7]);
            swap32(X2, Y2);
            u32x4 w = { X, X2, Y, Y2 };
            bf16x8 pa = __builtin_bit_cast(bf16x8, w);
            __builtin_amdgcn_s_setprio(1);
            #pragma unroll
            for (int nt = 0; nt < 2; ++nt) {
                const int dd = nt * 32 + q32;
                bf16x8 bb = *(const bf16x8*)(xktb + dd * 128 +
                                             (((2 * s + hi) ^ (q32 & 7)) << 4));
                Oacc[nt] = mfma32(pa, bb, Oacc[nt]);
            }
            __builtin_amdgcn_s_setprio(0);
        }
    };

    for (int kt = 0; kt < NKT; kt += 2) {
        body(kt, 0);
        body(kt + 1, 1);
    }

    // ---- epilogue: combine l partials + halves, broadcast 1/l, store ----
    {
        float l_run = (l4[0] + l4[1]) + (l4[2] + l4[3]);
        float lt = l_run + __shfl_xor(l_run, 32);
        if (hi == 0) sL[wave][q32] = 1.0f / lt;
    }
    __syncthreads();

    float* outb = out + ((size_t)bh * S_LEN + q0) * HD;
    #pragma unroll
    for (int r = 0; r < 16; ++r) {
        const int qlocal = 8 * (r >> 2) + 4 * hi + (r & 3);
        const float rl = sL[wave][qlocal];
        const int qrow = wbase + qlocal;
        #pragma unroll
        for (int nt = 0; nt < 2; ++nt)
            outb[(size_t)qrow * HD + nt * 32 + q32] = Oacc[nt][r] * rl;
    }
}

extern "C" void kernel_launch(void* const* d_in, const int* in_sizes, int n_in,
                              void* d_out, int out_size, void* d_ws, size_t ws_size,
                              hipStream_t stream) {
    const float* x    = (const float*)d_in[0];
    // d_in[1] (mask): per-(b,q) additive constant across keys -> softmax no-op.
    const float* W    = (const float*)d_in[2];
    const float* bvec = (const float*)d_in[3];

    bf16*  Mws = (bf16*)d_ws;                         // 8192 B
    float* Uws = (float*)((char*)d_ws + 8192);        // 256 B
    bf16*  Xbws = (bf16*)((char*)d_ws + 540672);      // 16777216 B
    bf16*  XTws = (bf16*)((char*)d_ws + 17317888);    // 16777216 B

    prex_kernel<<<dim3(33, 16, 4), dim3(256), 0, stream>>>(x, W, bvec,
                                                           Xbws, XTws, Uws, Mws);
    attn_kernel<<<dim3(64, 8, 1),  dim3(512), 0, stream>>>(Xbws, XTws, Mws, Uws,
                                                           (float*)d_out);
}